// Round 1
// baseline (2064.242 us; speedup 1.0000x reference)
//
#include <hip/hip_runtime.h>
#include <stdint.h>

#define T 4096
#define HDIM 1024
#define FDIM 4096
#define NE 8
#define MAXROWS 9216   // 72 tiles of 128; worst padded total = 8192 + 8*127 = 9208

typedef __bf16 bf16x8 __attribute__((ext_vector_type(8)));
typedef float f32x4 __attribute__((ext_vector_type(4)));

__device__ __forceinline__ unsigned short f2bf(float f) {
    unsigned u = __builtin_bit_cast(unsigned, f);
    u += 0x7FFFu + ((u >> 16) & 1u);   // RNE
    return (unsigned short)(u >> 16);
}

// ---------------- x -> bf16 ----------------
__global__ void conv_x_k(const float* __restrict__ x, unsigned short* __restrict__ xb) {
    size_t i = ((size_t)blockIdx.x * 256 + threadIdx.x) * 8;
    float4 a = *(const float4*)(x + i);
    float4 b = *(const float4*)(x + i + 4);
    uint4 v;
    v.x = (unsigned)f2bf(a.x) | ((unsigned)f2bf(a.y) << 16);
    v.y = (unsigned)f2bf(a.z) | ((unsigned)f2bf(a.w) << 16);
    v.z = (unsigned)f2bf(b.x) | ((unsigned)f2bf(b.y) << 16);
    v.w = (unsigned)f2bf(b.z) | ((unsigned)f2bf(b.w) << 16);
    *(uint4*)(xb + i) = v;
}

// ---------------- router: logits, top-2, append to expert lists ----------------
__global__ void router_k(const float* __restrict__ x, const float* __restrict__ gw,
                         float* __restrict__ logits_out, int* __restrict__ cnt,
                         int* __restrict__ list, float* __restrict__ wlist) {
    int w = threadIdx.x >> 6, lane = threadIdx.x & 63;
    int t = blockIdx.x * 4 + w;
    float acc[NE];
#pragma unroll
    for (int e = 0; e < NE; ++e) acc[e] = 0.f;
    for (int i = 0; i < HDIM / 64; ++i) {
        int h = i * 64 + lane;
        float xv = x[(size_t)t * HDIM + h];
#pragma unroll
        for (int e = 0; e < NE; ++e) acc[e] += xv * gw[e * HDIM + h];
    }
#pragma unroll
    for (int e = 0; e < NE; ++e)
#pragma unroll
        for (int off = 32; off; off >>= 1) acc[e] += __shfl_xor(acc[e], off);
    if (lane == 0) {
#pragma unroll
        for (int e = 0; e < NE; ++e) logits_out[(size_t)t * NE + e] = acc[e];
        int e1 = 0;
#pragma unroll
        for (int e = 1; e < NE; ++e) if (acc[e] > acc[e1]) e1 = e;
        int e2 = (e1 == 0) ? 1 : 0;
#pragma unroll
        for (int e = 0; e < NE; ++e) { if (e == e1) continue; if (acc[e] > acc[e2]) e2 = e; }
        // renormalized top-2 weights: p1/(p1+p2) = 1/(1+exp(l2-l1))
        float wa = 1.f / (1.f + expf(acc[e2] - acc[e1]));
        float wb = 1.f - wa;
        int p1 = atomicAdd(&cnt[e1], 1); list[e1 * T + p1] = t; wlist[e1 * T + p1] = wa;
        int p2 = atomicAdd(&cnt[e2], 1); list[e2 * T + p2] = t; wlist[e2 * T + p2] = wb;
    }
}

// ---------------- padded exclusive prefix over expert counts ----------------
__global__ void offsets_k(const int* __restrict__ cnt, int* __restrict__ poff) {
    if (threadIdx.x == 0) {
        int o = 0; poff[0] = 0;
        for (int e = 0; e < NE; ++e) { o += ((cnt[e] + 127) >> 7) << 7; poff[e + 1] = o; }
    }
}

// ---------------- compact lists into padded row space ----------------
__global__ void compact_k(const int* __restrict__ cnt, const int* __restrict__ poff,
                          const int* __restrict__ list, const float* __restrict__ wlist,
                          int* __restrict__ tok_row, float* __restrict__ w_row) {
    int gid = blockIdx.x * 256 + threadIdx.x;  // NE*T threads
    int e = gid >> 12, i = gid & (T - 1);
    int pc = poff[e + 1] - poff[e];
    if (i < pc) {
        int row = poff[e] + i;
        if (i < cnt[e]) { tok_row[row] = list[e * T + i]; w_row[row] = wlist[e * T + i]; }
        else           { tok_row[row] = -1;              w_row[row] = 0.f; }
    }
}

// ---------------- GEMM1: inter = silu(x@w1^T) * (x@w3^T), gathered rows ----------------
__global__ __launch_bounds__(256) void gemm1_k(
    const unsigned short* __restrict__ xb, const float* __restrict__ w1g,
    const float* __restrict__ w3g, const int* __restrict__ tok_row,
    const int* __restrict__ poff, unsigned short* __restrict__ inter,
    int f_base, int Fc) {

    __shared__ unsigned short As[128 * 64];
    __shared__ unsigned short B1[128 * 64];
    __shared__ unsigned short B3[128 * 64];
    __shared__ int toks[128];
    __shared__ int e_sh;

    int row0 = blockIdx.x * 128;
    int P = poff[NE];
    if (row0 >= P) return;
    int tid = threadIdx.x;
    if (tid == 0) { int e = 0; while (row0 >= poff[e + 1]) ++e; e_sh = e; }
    if (tid < 128) toks[tid] = tok_row[row0 + tid];
    __syncthreads();
    int e = e_sh;
    int fg0 = f_base + blockIdx.y * 128;
    const float* w1p = w1g + ((size_t)e * FDIM + fg0) * HDIM;
    const float* w3p = w3g + ((size_t)e * FDIM + fg0) * HDIM;

    int wv = tid >> 6, lane = tid & 63;
    int quad = lane >> 4, l16 = lane & 15;
    int wm = (wv >> 1) * 64, wn = (wv & 1) * 64;

    f32x4 acc1[4][4], acc3[4][4];
#pragma unroll
    for (int a = 0; a < 4; ++a)
#pragma unroll
        for (int b = 0; b < 4; ++b) {
            acc1[a][b] = f32x4{0.f, 0.f, 0.f, 0.f};
            acc3[a][b] = f32x4{0.f, 0.f, 0.f, 0.f};
        }

    for (int k0 = 0; k0 < HDIM; k0 += 64) {
        // stage A (gathered bf16 x rows): 128x64 bf16
#pragma unroll
        for (int it = 0; it < 4; ++it) {
            int u = tid + it * 256;
            int r = u >> 3, kg = u & 7;
            int t = toks[r];
            uint4 v = make_uint4(0u, 0u, 0u, 0u);
            if (t >= 0) v = *(const uint4*)(xb + (size_t)t * HDIM + k0 + kg * 8);
            *(uint4*)(As + r * 64 + kg * 8) = v;
        }
        // stage B1/B3 (fp32 -> bf16 convert): 128x64 each
#pragma unroll
        for (int it = 0; it < 8; ++it) {
            int u = tid + it * 256;
            int r = u >> 4, kg = u & 15;
            size_t so = (size_t)r * HDIM + k0 + kg * 4;
            float4 v1 = *(const float4*)(w1p + so);
            ushort4 s1; s1.x = f2bf(v1.x); s1.y = f2bf(v1.y); s1.z = f2bf(v1.z); s1.w = f2bf(v1.w);
            *(ushort4*)(B1 + r * 64 + kg * 4) = s1;
            float4 v3 = *(const float4*)(w3p + so);
            ushort4 s3; s3.x = f2bf(v3.x); s3.y = f2bf(v3.y); s3.z = f2bf(v3.z); s3.w = f2bf(v3.w);
            *(ushort4*)(B3 + r * 64 + kg * 4) = s3;
        }
        __syncthreads();
#pragma unroll
        for (int ks = 0; ks < 2; ++ks) {
            int kk = ks * 32 + quad * 8;
            bf16x8 af[4], b1f[4], b3f[4];
#pragma unroll
            for (int mi = 0; mi < 4; ++mi)
                af[mi] = *(const bf16x8*)(As + (wm + mi * 16 + l16) * 64 + kk);
#pragma unroll
            for (int ni = 0; ni < 4; ++ni) {
                b1f[ni] = *(const bf16x8*)(B1 + (wn + ni * 16 + l16) * 64 + kk);
                b3f[ni] = *(const bf16x8*)(B3 + (wn + ni * 16 + l16) * 64 + kk);
            }
#pragma unroll
            for (int mi = 0; mi < 4; ++mi)
#pragma unroll
                for (int ni = 0; ni < 4; ++ni) {
                    acc1[mi][ni] = __builtin_amdgcn_mfma_f32_16x16x32_bf16(af[mi], b1f[ni], acc1[mi][ni], 0, 0, 0);
                    acc3[mi][ni] = __builtin_amdgcn_mfma_f32_16x16x32_bf16(af[mi], b3f[ni], acc3[mi][ni], 0, 0, 0);
                }
        }
        __syncthreads();
    }
    int cb = blockIdx.y * 128;
#pragma unroll
    for (int mi = 0; mi < 4; ++mi)
#pragma unroll
        for (int ni = 0; ni < 4; ++ni)
#pragma unroll
            for (int r = 0; r < 4; ++r) {
                int m = wm + mi * 16 + quad * 4 + r;
                int n = wn + ni * 16 + l16;
                float v1 = acc1[mi][ni][r], v3 = acc3[mi][ni][r];
                float hval = (v1 / (1.f + __expf(-v1))) * v3;  // silu(v1)*v3
                inter[(size_t)(row0 + m) * Fc + cb + n] = f2bf(hval);
            }
}

// ---------------- GEMM2: out[tok] += w_row * (inter @ w2^T) ----------------
__global__ __launch_bounds__(256) void gemm2_k(
    const unsigned short* __restrict__ inter, const float* __restrict__ w2g,
    const int* __restrict__ tok_row, const float* __restrict__ w_row,
    const int* __restrict__ poff, float* __restrict__ out, int f_base, int Fc) {

    __shared__ unsigned short As[128 * 64];
    __shared__ unsigned short Bs[128 * 64];
    __shared__ int e_sh;

    int row0 = blockIdx.x * 128;
    int P = poff[NE];
    if (row0 >= P) return;
    int tid = threadIdx.x;
    if (tid == 0) { int e = 0; while (row0 >= poff[e + 1]) ++e; e_sh = e; }
    __syncthreads();
    int e = e_sh;
    int n0 = blockIdx.y * 128;
    const float* w2p = w2g + ((size_t)e * HDIM + n0) * FDIM + f_base;

    int wv = tid >> 6, lane = tid & 63;
    int quad = lane >> 4, l16 = lane & 15;
    int wm = (wv >> 1) * 64, wn = (wv & 1) * 64;

    f32x4 acc[4][4];
#pragma unroll
    for (int a = 0; a < 4; ++a)
#pragma unroll
        for (int b = 0; b < 4; ++b) acc[a][b] = f32x4{0.f, 0.f, 0.f, 0.f};

    for (int k0 = 0; k0 < Fc; k0 += 64) {
#pragma unroll
        for (int it = 0; it < 4; ++it) {
            int u = tid + it * 256;
            int r = u >> 3, kg = u & 7;
            uint4 v = *(const uint4*)(inter + (size_t)(row0 + r) * Fc + k0 + kg * 8);
            *(uint4*)(As + r * 64 + kg * 8) = v;
        }
#pragma unroll
        for (int it = 0; it < 8; ++it) {
            int u = tid + it * 256;
            int r = u >> 4, kg = u & 15;
            float4 v = *(const float4*)(w2p + (size_t)r * FDIM + k0 + kg * 4);
            ushort4 s; s.x = f2bf(v.x); s.y = f2bf(v.y); s.z = f2bf(v.z); s.w = f2bf(v.w);
            *(ushort4*)(Bs + r * 64 + kg * 4) = s;
        }
        __syncthreads();
#pragma unroll
        for (int ks = 0; ks < 2; ++ks) {
            int kk = ks * 32 + quad * 8;
            bf16x8 af[4], bf[4];
#pragma unroll
            for (int mi = 0; mi < 4; ++mi)
                af[mi] = *(const bf16x8*)(As + (wm + mi * 16 + l16) * 64 + kk);
#pragma unroll
            for (int ni = 0; ni < 4; ++ni)
                bf[ni] = *(const bf16x8*)(Bs + (wn + ni * 16 + l16) * 64 + kk);
#pragma unroll
            for (int mi = 0; mi < 4; ++mi)
#pragma unroll
                for (int ni = 0; ni < 4; ++ni)
                    acc[mi][ni] = __builtin_amdgcn_mfma_f32_16x16x32_bf16(af[mi], bf[ni], acc[mi][ni], 0, 0, 0);
        }
        __syncthreads();
    }
#pragma unroll
    for (int mi = 0; mi < 4; ++mi)
#pragma unroll
        for (int ni = 0; ni < 4; ++ni)
#pragma unroll
            for (int r = 0; r < 4; ++r) {
                int m = wm + mi * 16 + quad * 4 + r;
                int n = wn + ni * 16 + l16;
                int grow = row0 + m;
                int t = tok_row[grow];
                if (t >= 0)
                    atomicAdd(out + (size_t)t * HDIM + n0 + n, w_row[grow] * acc[mi][ni][r]);
            }
}

extern "C" void kernel_launch(void* const* d_in, const int* in_sizes, int n_in,
                              void* d_out, int out_size, void* d_ws, size_t ws_size,
                              hipStream_t stream) {
    const float* x  = (const float*)d_in[0];
    const float* gw = (const float*)d_in[1];
    const float* w1 = (const float*)d_in[2];
    const float* w2 = (const float*)d_in[3];
    const float* w3 = (const float*)d_in[4];
    float* out = (float*)d_out;
    float* logits = out + (size_t)T * HDIM;

    char* ws = (char*)d_ws;
    size_t off = 0;
    auto alloc = [&](size_t b) {
        off = (off + 255) & ~(size_t)255;
        void* p = ws + off;
        off += b;
        return p;
    };
    int* cnt        = (int*)alloc(NE * 4);
    int* poff       = (int*)alloc((NE + 1) * 4);
    int* list       = (int*)alloc((size_t)NE * T * 4);
    float* wlist    = (float*)alloc((size_t)NE * T * 4);
    int* tok_row    = (int*)alloc(MAXROWS * 4);
    float* w_row    = (float*)alloc(MAXROWS * 4);
    unsigned short* xb = (unsigned short*)alloc((size_t)T * HDIM * 2);
    off = (off + 255) & ~(size_t)255;
    // F-chunk size for the inter buffer, adapted to ws_size
    int Fc = FDIM;
    while (Fc > 512 && off + (size_t)MAXROWS * Fc * 2 > ws_size) Fc >>= 1;
    unsigned short* inter = (unsigned short*)(ws + off);

    hipMemsetAsync(cnt, 0, NE * 4, stream);
    hipMemsetAsync(out, 0, (size_t)T * HDIM * 4, stream);
    conv_x_k<<<(T * HDIM / 8) / 256, 256, 0, stream>>>(x, xb);
    router_k<<<T / 4, 256, 0, stream>>>(x, gw, logits, cnt, list, wlist);
    offsets_k<<<1, 64, 0, stream>>>(cnt, poff);
    compact_k<<<NE * T / 256, 256, 0, stream>>>(cnt, poff, list, wlist, tok_row, w_row);
    int nMT = MAXROWS / 128;  // 72
    for (int f_base = 0; f_base < FDIM; f_base += Fc) {
        gemm1_k<<<dim3(nMT, Fc / 128), 256, 0, stream>>>(xb, w1, w3, tok_row, poff, inter, f_base, Fc);
        gemm2_k<<<dim3(nMT, HDIM / 128), 256, 0, stream>>>(inter, w2, tok_row, w_row, poff, out, f_base, Fc);
    }
}

// Round 2
// 847.004 us; speedup vs baseline: 2.4371x; 2.4371x over previous
//
#include <hip/hip_runtime.h>
#include <stdint.h>

#define T 4096
#define HDIM 1024
#define FDIM 4096
#define NE 8
#define MAXROWS 9216   // 72 tiles of 128; worst padded total = 8192 + 8*127 = 9208

typedef __bf16 bf16x8 __attribute__((ext_vector_type(8)));
typedef float f32x4 __attribute__((ext_vector_type(4)));

__device__ __forceinline__ unsigned short f2bf(float f) {
    unsigned u = __builtin_bit_cast(unsigned, f);
    u += 0x7FFFu + ((u >> 16) & 1u);   // RNE
    return (unsigned short)(u >> 16);
}

// async 16B/lane global->LDS DMA: lds dest = base + lane*16 (wave-uniform base)
__device__ __forceinline__ void cp16(const void* g, const void* lds) {
    __builtin_amdgcn_global_load_lds(
        (const __attribute__((address_space(1))) unsigned int*)g,
        (__attribute__((address_space(3))) unsigned int*)(unsigned int)(unsigned long long)lds,
        16, 0, 0);
}

// ---------------- x -> bf16 (with one extra zero row appended by memset) ----
__global__ void conv_x_k(const float* __restrict__ x, unsigned short* __restrict__ xb) {
    size_t i = ((size_t)blockIdx.x * 256 + threadIdx.x) * 8;
    float4 a = *(const float4*)(x + i);
    float4 b = *(const float4*)(x + i + 4);
    uint4 v;
    v.x = (unsigned)f2bf(a.x) | ((unsigned)f2bf(a.y) << 16);
    v.y = (unsigned)f2bf(a.z) | ((unsigned)f2bf(a.w) << 16);
    v.z = (unsigned)f2bf(b.x) | ((unsigned)f2bf(b.y) << 16);
    v.w = (unsigned)f2bf(b.z) | ((unsigned)f2bf(b.w) << 16);
    *(uint4*)(xb + i) = v;
}

// ---------------- weight chunk converters (fp32 -> bf16) --------------------
// w1/w3: src [E][FDIM][H], take rows [f0,f0+Fc) -> dst [E][Fc][H]
__global__ void conv_w13_k(const float* __restrict__ src, unsigned short* __restrict__ dst,
                           int f0, int Fc) {
    int e = blockIdx.y;
    size_t rem = ((size_t)blockIdx.x * 256 + threadIdx.x) * 8;
    const float* s = src + ((size_t)e * FDIM + f0) * HDIM + rem;
    unsigned short* d = dst + (size_t)e * Fc * HDIM + rem;
    float4 a = *(const float4*)(s);
    float4 b = *(const float4*)(s + 4);
    uint4 v;
    v.x = (unsigned)f2bf(a.x) | ((unsigned)f2bf(a.y) << 16);
    v.y = (unsigned)f2bf(a.z) | ((unsigned)f2bf(a.w) << 16);
    v.z = (unsigned)f2bf(b.x) | ((unsigned)f2bf(b.y) << 16);
    v.w = (unsigned)f2bf(b.z) | ((unsigned)f2bf(b.w) << 16);
    *(uint4*)(d) = v;
}

// w2: src [E][H][FDIM], take cols [f0,f0+Fc) -> dst [E][H][Fc]
__global__ void conv_w2_k(const float* __restrict__ src, unsigned short* __restrict__ dst,
                          int f0, int Fc, int fcShift) {
    int e = blockIdx.y;
    size_t idx = ((size_t)blockIdx.x * 256 + threadIdx.x) * 8;
    int h = (int)(idx >> fcShift);
    int c = (int)(idx & (size_t)(Fc - 1));
    const float* s = src + ((size_t)e * HDIM + h) * FDIM + f0 + c;
    unsigned short* d = dst + (size_t)e * HDIM * Fc + idx;
    float4 a = *(const float4*)(s);
    float4 b = *(const float4*)(s + 4);
    uint4 v;
    v.x = (unsigned)f2bf(a.x) | ((unsigned)f2bf(a.y) << 16);
    v.y = (unsigned)f2bf(a.z) | ((unsigned)f2bf(a.w) << 16);
    v.z = (unsigned)f2bf(b.x) | ((unsigned)f2bf(b.y) << 16);
    v.w = (unsigned)f2bf(b.z) | ((unsigned)f2bf(b.w) << 16);
    *(uint4*)(d) = v;
}

// ---------------- router: logits, top-2, append to expert lists ----------------
__global__ void router_k(const float* __restrict__ x, const float* __restrict__ gw,
                         float* __restrict__ logits_out, int* __restrict__ cnt,
                         int* __restrict__ list, float* __restrict__ wlist) {
    int w = threadIdx.x >> 6, lane = threadIdx.x & 63;
    int t = blockIdx.x * 4 + w;
    float acc[NE];
#pragma unroll
    for (int e = 0; e < NE; ++e) acc[e] = 0.f;
    for (int i = 0; i < HDIM / 64; ++i) {
        int h = i * 64 + lane;
        float xv = x[(size_t)t * HDIM + h];
#pragma unroll
        for (int e = 0; e < NE; ++e) acc[e] += xv * gw[e * HDIM + h];
    }
#pragma unroll
    for (int e = 0; e < NE; ++e)
#pragma unroll
        for (int off = 32; off; off >>= 1) acc[e] += __shfl_xor(acc[e], off);
    if (lane == 0) {
#pragma unroll
        for (int e = 0; e < NE; ++e) logits_out[(size_t)t * NE + e] = acc[e];
        int e1 = 0;
#pragma unroll
        for (int e = 1; e < NE; ++e) if (acc[e] > acc[e1]) e1 = e;
        int e2 = (e1 == 0) ? 1 : 0;
#pragma unroll
        for (int e = 0; e < NE; ++e) { if (e == e1) continue; if (acc[e] > acc[e2]) e2 = e; }
        float wa = 1.f / (1.f + expf(acc[e2] - acc[e1]));
        float wb = 1.f - wa;
        int p1 = atomicAdd(&cnt[e1], 1); list[e1 * T + p1] = t; wlist[e1 * T + p1] = wa;
        int p2 = atomicAdd(&cnt[e2], 1); list[e2 * T + p2] = t; wlist[e2 * T + p2] = wb;
    }
}

// ---------------- padded exclusive prefix over expert counts ----------------
__global__ void offsets_k(const int* __restrict__ cnt, int* __restrict__ poff) {
    if (threadIdx.x == 0) {
        int o = 0; poff[0] = 0;
        for (int e = 0; e < NE; ++e) { o += ((cnt[e] + 127) >> 7) << 7; poff[e + 1] = o; }
    }
}

// ---------------- compact lists into padded row space ----------------
// pad rows get token index T (the zero row of xb) and weight 0
__global__ void compact_k(const int* __restrict__ cnt, const int* __restrict__ poff,
                          const int* __restrict__ list, const float* __restrict__ wlist,
                          int* __restrict__ tok_row, float* __restrict__ w_row) {
    int gid = blockIdx.x * 256 + threadIdx.x;  // NE*T threads
    int e = gid >> 12, i = gid & (T - 1);
    int pc = poff[e + 1] - poff[e];
    if (i < pc) {
        int row = poff[e] + i;
        if (i < cnt[e]) { tok_row[row] = list[e * T + i]; w_row[row] = wlist[e * T + i]; }
        else           { tok_row[row] = T;               w_row[row] = 0.f; }
    }
}

// ---------------- GEMM1: inter = silu(x@w1^T) * (x@w3^T), gathered rows ------
// All tiles staged with global_load_lds (16B/lane). XOR swizzle is applied on the
// GLOBAL source column so LDS reads are conflict-free without padding.
// LDS layout invariant: element (row r, colblk cb) of a 128x64 bf16 tile lives at
// byte (r>>3)*1024 + (r&7)*128 + (cb ^ (r&7))*16.
__global__ __launch_bounds__(256, 3) void gemm1_k(
    const unsigned short* __restrict__ xb, const unsigned short* __restrict__ wb1,
    const unsigned short* __restrict__ wb3, const int* __restrict__ tok_row,
    const int* __restrict__ poff, unsigned short* __restrict__ inter, int Fc) {

    __shared__ __align__(16) unsigned short As[128 * 64];
    __shared__ __align__(16) unsigned short B1[128 * 64];
    __shared__ __align__(16) unsigned short B3[128 * 64];
    __shared__ int toks[128];
    __shared__ int e_sh;

    int row0 = blockIdx.x * 128;
    if (row0 >= poff[NE]) return;
    int tid = threadIdx.x;
    if (tid == 0) { int e = 0; while (row0 >= poff[e + 1]) ++e; e_sh = e; }
    if (tid < 128) toks[tid] = tok_row[row0 + tid];
    __syncthreads();
    int e = e_sh;
    int fr0 = blockIdx.y * 128;   // row offset within the Fc chunk
    const unsigned short* w1p = wb1 + ((size_t)e * Fc + fr0) * HDIM;
    const unsigned short* w3p = wb3 + ((size_t)e * Fc + fr0) * HDIM;

    int wv = tid >> 6, lane = tid & 63;
    int quad = lane >> 4, l16 = lane & 15;
    int wm = (wv >> 1) * 64, wn = (wv & 1) * 64;

    // staging lane geometry: lane covers (row 8j+sr, colblk sc^sr) of instruction j
    int sr = lane >> 3;
    int sc = (lane & 7) ^ sr;
    // per-lane global element offsets
    unsigned a_off[4];
#pragma unroll
    for (int jj = 0; jj < 4; ++jj)
        a_off[jj] = (unsigned)toks[wv * 32 + jj * 8 + sr] * HDIM + sc * 8;
    const unsigned short* w1b = w1p + (size_t)(wv * 32 + sr) * HDIM + sc * 8;
    const unsigned short* w3b = w3p + (size_t)(wv * 32 + sr) * HDIM + sc * 8;

    f32x4 acc1[4][4], acc3[4][4];
#pragma unroll
    for (int a = 0; a < 4; ++a)
#pragma unroll
        for (int b = 0; b < 4; ++b) {
            acc1[a][b] = f32x4{0.f, 0.f, 0.f, 0.f};
            acc3[a][b] = f32x4{0.f, 0.f, 0.f, 0.f};
        }

    for (int k0 = 0; k0 < HDIM; k0 += 64) {
#pragma unroll
        for (int jj = 0; jj < 4; ++jj) {
            int j = wv * 4 + jj;
            cp16(xb + a_off[jj] + k0, As + j * 512);
            cp16(w1b + (size_t)jj * 8 * HDIM + k0, B1 + j * 512);
            cp16(w3b + (size_t)jj * 8 * HDIM + k0, B3 + j * 512);
        }
        __syncthreads();
#pragma unroll
        for (int ks = 0; ks < 2; ++ks) {
            int cb0 = ks * 4 + quad;   // colblk index 0..7 (8 bf16 each)
            bf16x8 af[4];
#pragma unroll
            for (int mi = 0; mi < 4; ++mi) {
                int m = wm + mi * 16 + l16;
                af[mi] = *(const bf16x8*)(As + m * 64 + ((cb0 ^ (m & 7)) * 8));
            }
#pragma unroll
            for (int ni = 0; ni < 4; ++ni) {
                int n = wn + ni * 16 + l16;
                int boff = n * 64 + ((cb0 ^ (n & 7)) * 8);
                bf16x8 b1f = *(const bf16x8*)(B1 + boff);
                bf16x8 b3f = *(const bf16x8*)(B3 + boff);
#pragma unroll
                for (int mi = 0; mi < 4; ++mi) {
                    acc1[mi][ni] = __builtin_amdgcn_mfma_f32_16x16x32_bf16(af[mi], b1f, acc1[mi][ni], 0, 0, 0);
                    acc3[mi][ni] = __builtin_amdgcn_mfma_f32_16x16x32_bf16(af[mi], b3f, acc3[mi][ni], 0, 0, 0);
                }
            }
        }
        __syncthreads();
    }
#pragma unroll
    for (int mi = 0; mi < 4; ++mi)
#pragma unroll
        for (int ni = 0; ni < 4; ++ni)
#pragma unroll
            for (int r = 0; r < 4; ++r) {
                int m = wm + mi * 16 + quad * 4 + r;
                int n = wn + ni * 16 + l16;
                float v1 = acc1[mi][ni][r], v3 = acc3[mi][ni][r];
                float hval = (v1 / (1.f + __expf(-v1))) * v3;  // silu(v1)*v3
                inter[(size_t)(row0 + m) * Fc + fr0 + n] = f2bf(hval);
            }
}

// ---------------- GEMM2: out[tok] += w_row * (inter @ w2^T) ----------------
__global__ __launch_bounds__(256, 3) void gemm2_k(
    const unsigned short* __restrict__ inter, const unsigned short* __restrict__ wb2,
    const int* __restrict__ tok_row, const float* __restrict__ w_row,
    const int* __restrict__ poff, float* __restrict__ out, int Fc) {

    __shared__ __align__(16) unsigned short As[128 * 64];
    __shared__ __align__(16) unsigned short Bs[128 * 64];
    __shared__ int e_sh;

    int row0 = blockIdx.x * 128;
    if (row0 >= poff[NE]) return;
    int tid = threadIdx.x;
    if (tid == 0) { int e = 0; while (row0 >= poff[e + 1]) ++e; e_sh = e; }
    __syncthreads();
    int e = e_sh;
    int n0 = blockIdx.y * 128;

    int wv = tid >> 6, lane = tid & 63;
    int quad = lane >> 4, l16 = lane & 15;
    int wm = (wv >> 1) * 64, wn = (wv & 1) * 64;

    int sr = lane >> 3;
    int sc = (lane & 7) ^ sr;
    const unsigned short* a_b = inter + (size_t)(row0 + wv * 32 + sr) * Fc + sc * 8;
    const unsigned short* b_b = wb2 + ((size_t)e * HDIM + n0 + wv * 32 + sr) * Fc + sc * 8;

    f32x4 acc[4][4];
#pragma unroll
    for (int a = 0; a < 4; ++a)
#pragma unroll
        for (int b = 0; b < 4; ++b) acc[a][b] = f32x4{0.f, 0.f, 0.f, 0.f};

    for (int k0 = 0; k0 < Fc; k0 += 64) {
#pragma unroll
        for (int jj = 0; jj < 4; ++jj) {
            int j = wv * 4 + jj;
            cp16(a_b + (size_t)jj * 8 * Fc + k0, As + j * 512);
            cp16(b_b + (size_t)jj * 8 * Fc + k0, Bs + j * 512);
        }
        __syncthreads();
#pragma unroll
        for (int ks = 0; ks < 2; ++ks) {
            int cb0 = ks * 4 + quad;
            bf16x8 af[4];
#pragma unroll
            for (int mi = 0; mi < 4; ++mi) {
                int m = wm + mi * 16 + l16;
                af[mi] = *(const bf16x8*)(As + m * 64 + ((cb0 ^ (m & 7)) * 8));
            }
#pragma unroll
            for (int ni = 0; ni < 4; ++ni) {
                int n = wn + ni * 16 + l16;
                bf16x8 bf = *(const bf16x8*)(Bs + n * 64 + ((cb0 ^ (n & 7)) * 8));
#pragma unroll
                for (int mi = 0; mi < 4; ++mi)
                    acc[mi][ni] = __builtin_amdgcn_mfma_f32_16x16x32_bf16(af[mi], bf, acc[mi][ni], 0, 0, 0);
            }
        }
        __syncthreads();
    }
#pragma unroll
    for (int mi = 0; mi < 4; ++mi)
#pragma unroll
        for (int ni = 0; ni < 4; ++ni)
#pragma unroll
            for (int r = 0; r < 4; ++r) {
                int m = wm + mi * 16 + quad * 4 + r;
                int n = wn + ni * 16 + l16;
                int grow = row0 + m;
                float wr = w_row[grow];
                if (wr != 0.f) {
                    int t = tok_row[grow];
                    atomicAdd(out + (size_t)t * HDIM + n0 + n, wr * acc[mi][ni][r]);
                }
            }
}

extern "C" void kernel_launch(void* const* d_in, const int* in_sizes, int n_in,
                              void* d_out, int out_size, void* d_ws, size_t ws_size,
                              hipStream_t stream) {
    const float* x  = (const float*)d_in[0];
    const float* gw = (const float*)d_in[1];
    const float* w1 = (const float*)d_in[2];
    const float* w2 = (const float*)d_in[3];
    const float* w3 = (const float*)d_in[4];
    float* out = (float*)d_out;
    float* logits = out + (size_t)T * HDIM;

    char* ws = (char*)d_ws;
    size_t off = 0;
    auto alloc = [&](size_t b) {
        off = (off + 255) & ~(size_t)255;
        void* p = ws + off;
        off += b;
        return p;
    };
    int* cnt        = (int*)alloc(NE * 4);
    int* poff       = (int*)alloc((NE + 1) * 4);
    int* list       = (int*)alloc((size_t)NE * T * 4);
    float* wlist    = (float*)alloc((size_t)NE * T * 4);
    int* tok_row    = (int*)alloc(MAXROWS * 4);
    float* w_row    = (float*)alloc(MAXROWS * 4);
    unsigned short* xb = (unsigned short*)alloc((size_t)(T + 1) * HDIM * 2);  // +1 zero row
    size_t fixed_off = off;

    // pick largest F-chunk that fits: 3 bf16 weight chunk buffers + inter
    int Fc = 4096, fcShift = 12;
    for (;;) {
        size_t need = fixed_off + 3 * ((size_t)NE * Fc * HDIM * 2) + (size_t)MAXROWS * Fc * 2 + 1024;
        if (need <= ws_size || Fc == 512) break;
        Fc >>= 1; fcShift -= 1;
    }
    unsigned short* wb1 = (unsigned short*)alloc((size_t)NE * Fc * HDIM * 2);
    unsigned short* wb3 = (unsigned short*)alloc((size_t)NE * Fc * HDIM * 2);
    unsigned short* wb2 = (unsigned short*)alloc((size_t)NE * HDIM * Fc * 2);
    unsigned short* inter = (unsigned short*)alloc((size_t)MAXROWS * Fc * 2);

    hipMemsetAsync(cnt, 0, NE * 4, stream);
    hipMemsetAsync(out, 0, (size_t)T * HDIM * 4, stream);
    hipMemsetAsync(xb + (size_t)T * HDIM, 0, HDIM * 2, stream);  // zero row for pad tokens
    conv_x_k<<<(T * HDIM / 8) / 256, 256, 0, stream>>>(x, xb);
    router_k<<<T / 4, 256, 0, stream>>>(x, gw, logits, cnt, list, wlist);
    offsets_k<<<1, 64, 0, stream>>>(cnt, poff);
    compact_k<<<NE * T / 256, 256, 0, stream>>>(cnt, poff, list, wlist, tok_row, w_row);

    int nMT = MAXROWS / 128;  // 72
    for (int f0 = 0; f0 < FDIM; f0 += Fc) {
        conv_w13_k<<<dim3(Fc / 2, NE), 256, 0, stream>>>(w1, wb1, f0, Fc);
        conv_w13_k<<<dim3(Fc / 2, NE), 256, 0, stream>>>(w3, wb3, f0, Fc);
        conv_w2_k<<<dim3(HDIM * Fc / 2048, NE), 256, 0, stream>>>(w2, wb2, f0, Fc, fcShift);
        gemm1_k<<<dim3(nMT, Fc / 128), 256, 0, stream>>>(xb, wb1, wb3, tok_row, poff, inter, Fc);
        gemm2_k<<<dim3(nMT, HDIM / 128), 256, 0, stream>>>(inter, wb2, tok_row, w_row, poff, out, Fc);
    }
}

// Round 3
// 844.159 us; speedup vs baseline: 2.4453x; 1.0034x over previous
//
#include <hip/hip_runtime.h>
#include <stdint.h>

#define T 4096
#define HDIM 1024
#define FDIM 4096
#define NE 8
#define MAXROWS 9216   // 72 tiles of 128; worst padded total = 8192 + 8*127 = 9208

typedef __bf16 bf16x8 __attribute__((ext_vector_type(8)));
typedef float f32x4 __attribute__((ext_vector_type(4)));

__device__ __forceinline__ unsigned short f2bf(float f) {
    unsigned u = __builtin_bit_cast(unsigned, f);
    u += 0x7FFFu + ((u >> 16) & 1u);   // RNE
    return (unsigned short)(u >> 16);
}

// async 16B/lane global->LDS DMA: lds dest = base + lane*16 (wave-uniform base)
__device__ __forceinline__ void cp16(const void* g, const void* lds) {
    __builtin_amdgcn_global_load_lds(
        (const __attribute__((address_space(1))) unsigned int*)g,
        (__attribute__((address_space(3))) unsigned int*)(unsigned int)(unsigned long long)lds,
        16, 0, 0);
}

// ---------------- x -> bf16 (with one extra zero row appended by memset) ----
__global__ void conv_x_k(const float* __restrict__ x, unsigned short* __restrict__ xb) {
    size_t i = ((size_t)blockIdx.x * 256 + threadIdx.x) * 8;
    float4 a = *(const float4*)(x + i);
    float4 b = *(const float4*)(x + i + 4);
    uint4 v;
    v.x = (unsigned)f2bf(a.x) | ((unsigned)f2bf(a.y) << 16);
    v.y = (unsigned)f2bf(a.z) | ((unsigned)f2bf(a.w) << 16);
    v.z = (unsigned)f2bf(b.x) | ((unsigned)f2bf(b.y) << 16);
    v.w = (unsigned)f2bf(b.z) | ((unsigned)f2bf(b.w) << 16);
    *(uint4*)(xb + i) = v;
}

// ---------------- merged weight converter (full-F path): all 3 tensors ------
__global__ void conv_all_k(const float* __restrict__ w1, const float* __restrict__ w3,
                           const float* __restrict__ w2,
                           unsigned short* __restrict__ wb1, unsigned short* __restrict__ wb3,
                           unsigned short* __restrict__ wb2) {
    int z = blockIdx.y;
    const float* s = (z == 0) ? w1 : (z == 1) ? w3 : w2;
    unsigned short* d = (z == 0) ? wb1 : (z == 1) ? wb3 : wb2;
    size_t i = ((size_t)blockIdx.x * 256 + threadIdx.x) * 8;
    float4 a = *(const float4*)(s + i);
    float4 b = *(const float4*)(s + i + 4);
    uint4 v;
    v.x = (unsigned)f2bf(a.x) | ((unsigned)f2bf(a.y) << 16);
    v.y = (unsigned)f2bf(a.z) | ((unsigned)f2bf(a.w) << 16);
    v.z = (unsigned)f2bf(b.x) | ((unsigned)f2bf(b.y) << 16);
    v.w = (unsigned)f2bf(b.z) | ((unsigned)f2bf(b.w) << 16);
    *(uint4*)(d + i) = v;
}

// ---------------- chunked weight converters (fallback when ws is small) -----
__global__ void conv_w13_k(const float* __restrict__ src, unsigned short* __restrict__ dst,
                           int f0, int Fc) {
    int e = blockIdx.y;
    size_t rem = ((size_t)blockIdx.x * 256 + threadIdx.x) * 8;
    const float* s = src + ((size_t)e * FDIM + f0) * HDIM + rem;
    unsigned short* d = dst + (size_t)e * Fc * HDIM + rem;
    float4 a = *(const float4*)(s);
    float4 b = *(const float4*)(s + 4);
    uint4 v;
    v.x = (unsigned)f2bf(a.x) | ((unsigned)f2bf(a.y) << 16);
    v.y = (unsigned)f2bf(a.z) | ((unsigned)f2bf(a.w) << 16);
    v.z = (unsigned)f2bf(b.x) | ((unsigned)f2bf(b.y) << 16);
    v.w = (unsigned)f2bf(b.z) | ((unsigned)f2bf(b.w) << 16);
    *(uint4*)(d) = v;
}

__global__ void conv_w2_k(const float* __restrict__ src, unsigned short* __restrict__ dst,
                          int f0, int Fc, int fcShift) {
    int e = blockIdx.y;
    size_t idx = ((size_t)blockIdx.x * 256 + threadIdx.x) * 8;
    int h = (int)(idx >> fcShift);
    int c = (int)(idx & (size_t)(Fc - 1));
    const float* s = src + ((size_t)e * HDIM + h) * FDIM + f0 + c;
    unsigned short* d = dst + (size_t)e * HDIM * Fc + idx;
    float4 a = *(const float4*)(s);
    float4 b = *(const float4*)(s + 4);
    uint4 v;
    v.x = (unsigned)f2bf(a.x) | ((unsigned)f2bf(a.y) << 16);
    v.y = (unsigned)f2bf(a.z) | ((unsigned)f2bf(a.w) << 16);
    v.z = (unsigned)f2bf(b.x) | ((unsigned)f2bf(b.y) << 16);
    v.w = (unsigned)f2bf(b.z) | ((unsigned)f2bf(b.w) << 16);
    *(uint4*)(d) = v;
}

// ---------------- router: logits, top-2, append to expert lists ----------------
__global__ void router_k(const float* __restrict__ x, const float* __restrict__ gw,
                         float* __restrict__ logits_out, int* __restrict__ cnt,
                         int* __restrict__ list, float* __restrict__ wlist) {
    int w = threadIdx.x >> 6, lane = threadIdx.x & 63;
    int t = blockIdx.x * 4 + w;
    float acc[NE];
#pragma unroll
    for (int e = 0; e < NE; ++e) acc[e] = 0.f;
    for (int i = 0; i < HDIM / 64; ++i) {
        int h = i * 64 + lane;
        float xv = x[(size_t)t * HDIM + h];
#pragma unroll
        for (int e = 0; e < NE; ++e) acc[e] += xv * gw[e * HDIM + h];
    }
#pragma unroll
    for (int e = 0; e < NE; ++e)
#pragma unroll
        for (int off = 32; off; off >>= 1) acc[e] += __shfl_xor(acc[e], off);
    if (lane == 0) {
#pragma unroll
        for (int e = 0; e < NE; ++e) logits_out[(size_t)t * NE + e] = acc[e];
        int e1 = 0;
#pragma unroll
        for (int e = 1; e < NE; ++e) if (acc[e] > acc[e1]) e1 = e;
        int e2 = (e1 == 0) ? 1 : 0;
#pragma unroll
        for (int e = 0; e < NE; ++e) { if (e == e1) continue; if (acc[e] > acc[e2]) e2 = e; }
        float wa = 1.f / (1.f + expf(acc[e2] - acc[e1]));
        float wb = 1.f - wa;
        int p1 = atomicAdd(&cnt[e1], 1); list[e1 * T + p1] = t; wlist[e1 * T + p1] = wa;
        int p2 = atomicAdd(&cnt[e2], 1); list[e2 * T + p2] = t; wlist[e2 * T + p2] = wb;
    }
}

// ---------------- padded exclusive prefix over expert counts ----------------
__global__ void offsets_k(const int* __restrict__ cnt, int* __restrict__ poff) {
    if (threadIdx.x == 0) {
        int o = 0; poff[0] = 0;
        for (int e = 0; e < NE; ++e) { o += ((cnt[e] + 127) >> 7) << 7; poff[e + 1] = o; }
    }
}

// ---------------- compact lists into padded row space ----------------
// pad rows get token index T (the zero row of xb) and weight 0
__global__ void compact_k(const int* __restrict__ cnt, const int* __restrict__ poff,
                          const int* __restrict__ list, const float* __restrict__ wlist,
                          int* __restrict__ tok_row, float* __restrict__ w_row) {
    int gid = blockIdx.x * 256 + threadIdx.x;  // NE*T threads
    int e = gid >> 12, i = gid & (T - 1);
    int pc = poff[e + 1] - poff[e];
    if (i < pc) {
        int row = poff[e] + i;
        if (i < cnt[e]) { tok_row[row] = list[e * T + i]; w_row[row] = wlist[e * T + i]; }
        else           { tok_row[row] = T;               w_row[row] = 0.f; }
    }
}

// ---------------- GEMM1: inter = silu(x@w1^T) * (x@w3^T), gathered rows ------
// LDS layout invariant: element (row r, colblk cb) of a Nx64 bf16 tile lives at
// byte (r>>3)*1024 + (r&7)*128 + (cb ^ (r&7))*16  (swizzle applied on GLOBAL col).
__global__ __launch_bounds__(256, 3) void gemm1_k(
    const unsigned short* __restrict__ xb, const unsigned short* __restrict__ wb1,
    const unsigned short* __restrict__ wb3, const int* __restrict__ tok_row,
    const int* __restrict__ poff, unsigned short* __restrict__ inter, int Fc) {

    __shared__ __align__(16) unsigned short As[128 * 64];
    __shared__ __align__(16) unsigned short B1[128 * 64];
    __shared__ __align__(16) unsigned short B3[128 * 64];
    __shared__ int toks[128];
    __shared__ int e_sh;

    int row0 = blockIdx.x * 128;
    if (row0 >= poff[NE]) return;
    int tid = threadIdx.x;
    if (tid == 0) { int e = 0; while (row0 >= poff[e + 1]) ++e; e_sh = e; }
    if (tid < 128) toks[tid] = tok_row[row0 + tid];
    __syncthreads();
    int e = e_sh;
    int fr0 = blockIdx.y * 128;
    const unsigned short* w1p = wb1 + ((size_t)e * Fc + fr0) * HDIM;
    const unsigned short* w3p = wb3 + ((size_t)e * Fc + fr0) * HDIM;

    int wv = tid >> 6, lane = tid & 63;
    int quad = lane >> 4, l16 = lane & 15;
    int wm = (wv >> 1) * 64, wn = (wv & 1) * 64;

    int sr = lane >> 3;
    int sc = (lane & 7) ^ sr;
    unsigned a_off[4];
#pragma unroll
    for (int jj = 0; jj < 4; ++jj)
        a_off[jj] = (unsigned)toks[wv * 32 + jj * 8 + sr] * HDIM + sc * 8;
    const unsigned short* w1b = w1p + (size_t)(wv * 32 + sr) * HDIM + sc * 8;
    const unsigned short* w3b = w3p + (size_t)(wv * 32 + sr) * HDIM + sc * 8;

    f32x4 acc1[4][4], acc3[4][4];
#pragma unroll
    for (int a = 0; a < 4; ++a)
#pragma unroll
        for (int b = 0; b < 4; ++b) {
            acc1[a][b] = f32x4{0.f, 0.f, 0.f, 0.f};
            acc3[a][b] = f32x4{0.f, 0.f, 0.f, 0.f};
        }

    for (int k0 = 0; k0 < HDIM; k0 += 64) {
#pragma unroll
        for (int jj = 0; jj < 4; ++jj) {
            int j = wv * 4 + jj;
            cp16(xb + a_off[jj] + k0, As + j * 512);
            cp16(w1b + (size_t)jj * 8 * HDIM + k0, B1 + j * 512);
            cp16(w3b + (size_t)jj * 8 * HDIM + k0, B3 + j * 512);
        }
        __syncthreads();
#pragma unroll
        for (int ks = 0; ks < 2; ++ks) {
            int cb0 = ks * 4 + quad;
            bf16x8 af[4];
#pragma unroll
            for (int mi = 0; mi < 4; ++mi) {
                int m = wm + mi * 16 + l16;
                af[mi] = *(const bf16x8*)(As + m * 64 + ((cb0 ^ (m & 7)) * 8));
            }
#pragma unroll
            for (int ni = 0; ni < 4; ++ni) {
                int n = wn + ni * 16 + l16;
                int boff = n * 64 + ((cb0 ^ (n & 7)) * 8);
                bf16x8 b1f = *(const bf16x8*)(B1 + boff);
                bf16x8 b3f = *(const bf16x8*)(B3 + boff);
#pragma unroll
                for (int mi = 0; mi < 4; ++mi) {
                    acc1[mi][ni] = __builtin_amdgcn_mfma_f32_16x16x32_bf16(af[mi], b1f, acc1[mi][ni], 0, 0, 0);
                    acc3[mi][ni] = __builtin_amdgcn_mfma_f32_16x16x32_bf16(af[mi], b3f, acc3[mi][ni], 0, 0, 0);
                }
            }
        }
        __syncthreads();
    }
#pragma unroll
    for (int mi = 0; mi < 4; ++mi)
#pragma unroll
        for (int ni = 0; ni < 4; ++ni)
#pragma unroll
            for (int r = 0; r < 4; ++r) {
                int m = wm + mi * 16 + quad * 4 + r;
                int n = wn + ni * 16 + l16;
                float v1 = acc1[mi][ni][r], v3 = acc3[mi][ni][r];
                float hval = (v1 / (1.f + __expf(-v1))) * v3;  // silu(v1)*v3
                inter[(size_t)(row0 + m) * Fc + fr0 + n] = f2bf(hval);
            }
}

// ---------------- GEMM2: out[tok] += w_row * (inter @ w2^T) ----------------
// 512 threads, M=128 x N=256 tile, 8 waves of 64x64. Per barrier-pair the block
// does 256 MFMA on 48 KB staged — same ratio as gemm1 (old gemm2 was half).
__global__ __launch_bounds__(512, 4) void gemm2_k(
    const unsigned short* __restrict__ inter, const unsigned short* __restrict__ wb2,
    const int* __restrict__ tok_row, const float* __restrict__ w_row,
    const int* __restrict__ poff, float* __restrict__ out, int Fc) {

    __shared__ __align__(16) unsigned short As[128 * 64];   // 16 KB
    __shared__ __align__(16) unsigned short Bs[256 * 64];   // 32 KB
    __shared__ int e_sh;

    int row0 = blockIdx.x * 128;
    if (row0 >= poff[NE]) return;
    int tid = threadIdx.x;
    if (tid == 0) { int e = 0; while (row0 >= poff[e + 1]) ++e; e_sh = e; }
    __syncthreads();
    int e = e_sh;
    int n0 = blockIdx.y * 256;

    int wv = tid >> 6, lane = tid & 63;
    int quad = lane >> 4, l16 = lane & 15;
    int wm = (wv & 1) * 64;       // 2 wave-rows x 64
    int wn = (wv >> 1) * 64;      // 4 wave-cols x 64

    int sr = lane >> 3;
    int sc = (lane & 7) ^ sr;
    // A: 16 cp16 instrs (128 rows), wave issues 2; B: 32 instrs (256 rows), wave issues 4
    const unsigned short* a_b = inter + (size_t)(row0 + wv * 16 + sr) * Fc + sc * 8;
    const unsigned short* b_b = wb2 + ((size_t)e * HDIM + n0 + wv * 32 + sr) * Fc + sc * 8;

    f32x4 acc[4][4];
#pragma unroll
    for (int a = 0; a < 4; ++a)
#pragma unroll
        for (int b = 0; b < 4; ++b) acc[a][b] = f32x4{0.f, 0.f, 0.f, 0.f};

    for (int k0 = 0; k0 < Fc; k0 += 64) {
#pragma unroll
        for (int jj = 0; jj < 2; ++jj)
            cp16(a_b + (size_t)jj * 8 * Fc + k0, As + (wv * 2 + jj) * 512);
#pragma unroll
        for (int jj = 0; jj < 4; ++jj)
            cp16(b_b + (size_t)jj * 8 * Fc + k0, Bs + (wv * 4 + jj) * 512);
        __syncthreads();
#pragma unroll
        for (int ks = 0; ks < 2; ++ks) {
            int cb0 = ks * 4 + quad;
            bf16x8 af[4];
#pragma unroll
            for (int mi = 0; mi < 4; ++mi) {
                int m = wm + mi * 16 + l16;
                af[mi] = *(const bf16x8*)(As + m * 64 + ((cb0 ^ (m & 7)) * 8));
            }
#pragma unroll
            for (int ni = 0; ni < 4; ++ni) {
                int n = wn + ni * 16 + l16;
                bf16x8 bf = *(const bf16x8*)(Bs + n * 64 + ((cb0 ^ (n & 7)) * 8));
#pragma unroll
                for (int mi = 0; mi < 4; ++mi)
                    acc[mi][ni] = __builtin_amdgcn_mfma_f32_16x16x32_bf16(af[mi], bf, acc[mi][ni], 0, 0, 0);
            }
        }
        __syncthreads();
    }
#pragma unroll
    for (int mi = 0; mi < 4; ++mi)
#pragma unroll
        for (int r = 0; r < 4; ++r) {
            int m = wm + mi * 16 + quad * 4 + r;
            int grow = row0 + m;
            float wr = w_row[grow];
            if (wr != 0.f) {
                int t = tok_row[grow];
                float* op = out + (size_t)t * HDIM + n0;
#pragma unroll
                for (int ni = 0; ni < 4; ++ni)
                    atomicAdd(op + wn + ni * 16 + l16, wr * acc[mi][ni][r]);
            }
        }
}

extern "C" void kernel_launch(void* const* d_in, const int* in_sizes, int n_in,
                              void* d_out, int out_size, void* d_ws, size_t ws_size,
                              hipStream_t stream) {
    const float* x  = (const float*)d_in[0];
    const float* gw = (const float*)d_in[1];
    const float* w1 = (const float*)d_in[2];
    const float* w2 = (const float*)d_in[3];
    const float* w3 = (const float*)d_in[4];
    float* out = (float*)d_out;
    float* logits = out + (size_t)T * HDIM;

    char* ws = (char*)d_ws;
    size_t off = 0;
    auto alloc = [&](size_t b) {
        off = (off + 255) & ~(size_t)255;
        void* p = ws + off;
        off += b;
        return p;
    };
    int* cnt        = (int*)alloc(NE * 4);
    int* poff       = (int*)alloc((NE + 1) * 4);
    int* list       = (int*)alloc((size_t)NE * T * 4);
    float* wlist    = (float*)alloc((size_t)NE * T * 4);
    int* tok_row    = (int*)alloc(MAXROWS * 4);
    float* w_row    = (float*)alloc(MAXROWS * 4);
    unsigned short* xb = (unsigned short*)alloc((size_t)(T + 1) * HDIM * 2);  // +1 zero row
    size_t fixed_off = off;

    int Fc = 4096, fcShift = 12;
    for (;;) {
        size_t need = fixed_off + 3 * ((size_t)NE * Fc * HDIM * 2) + (size_t)MAXROWS * Fc * 2 + 1024;
        if (need <= ws_size || Fc == 512) break;
        Fc >>= 1; fcShift -= 1;
    }
    unsigned short* wb1 = (unsigned short*)alloc((size_t)NE * Fc * HDIM * 2);
    unsigned short* wb3 = (unsigned short*)alloc((size_t)NE * Fc * HDIM * 2);
    unsigned short* wb2 = (unsigned short*)alloc((size_t)NE * HDIM * Fc * 2);
    unsigned short* inter = (unsigned short*)alloc((size_t)MAXROWS * Fc * 2);

    hipMemsetAsync(cnt, 0, NE * 4, stream);
    hipMemsetAsync(out, 0, (size_t)T * HDIM * 4, stream);
    hipMemsetAsync(xb + (size_t)T * HDIM, 0, HDIM * 2, stream);
    conv_x_k<<<(T * HDIM / 8) / 256, 256, 0, stream>>>(x, xb);
    router_k<<<T / 4, 256, 0, stream>>>(x, gw, logits, cnt, list, wlist);
    offsets_k<<<1, 64, 0, stream>>>(cnt, poff);
    compact_k<<<NE * T / 256, 256, 0, stream>>>(cnt, poff, list, wlist, tok_row, w_row);

    int nMT = MAXROWS / 128;  // 72
    if (Fc == FDIM) {
        conv_all_k<<<dim3((size_t)NE * FDIM * HDIM / 8 / 256, 3), 256, 0, stream>>>(
            w1, w3, w2, wb1, wb3, wb2);
        gemm1_k<<<dim3(nMT, FDIM / 128), 256, 0, stream>>>(xb, wb1, wb3, tok_row, poff, inter, FDIM);
        gemm2_k<<<dim3(nMT, HDIM / 256), 512, 0, stream>>>(inter, wb2, tok_row, w_row, poff, out, FDIM);
    } else {
        for (int f0 = 0; f0 < FDIM; f0 += Fc) {
            conv_w13_k<<<dim3(Fc / 2, NE), 256, 0, stream>>>(w1, wb1, f0, Fc);
            conv_w13_k<<<dim3(Fc / 2, NE), 256, 0, stream>>>(w3, wb3, f0, Fc);
            conv_w2_k<<<dim3(HDIM * Fc / 2048, NE), 256, 0, stream>>>(w2, wb2, f0, Fc, fcShift);
            gemm1_k<<<dim3(nMT, Fc / 128), 256, 0, stream>>>(xb, wb1, wb3, tok_row, poff, inter, Fc);
            gemm2_k<<<dim3(nMT, HDIM / 256), 512, 0, stream>>>(inter, wb2, tok_row, w_row, poff, out, Fc);
        }
    }
}

// Round 4
// 797.883 us; speedup vs baseline: 2.5871x; 1.0580x over previous
//
#include <hip/hip_runtime.h>
#include <stdint.h>

#define T 4096
#define HDIM 1024
#define FDIM 4096
#define NE 8
#define MAXROWS 9216   // 72 tiles of 128; worst padded total = 8192 + 8*127 = 9208

typedef __bf16 bf16x8 __attribute__((ext_vector_type(8)));
typedef float f32x4 __attribute__((ext_vector_type(4)));

__device__ __forceinline__ unsigned short f2bf(float f) {
    unsigned u = __builtin_bit_cast(unsigned, f);
    u += 0x7FFFu + ((u >> 16) & 1u);   // RNE
    return (unsigned short)(u >> 16);
}

// async 16B/lane global->LDS DMA: lds dest = base + lane*16 (wave-uniform base)
__device__ __forceinline__ void cp16(const void* g, const void* lds) {
    __builtin_amdgcn_global_load_lds(
        (const __attribute__((address_space(1))) unsigned int*)g,
        (__attribute__((address_space(3))) unsigned int*)(unsigned int)(unsigned long long)lds,
        16, 0, 0);
}

// ---------------- x -> bf16 (with one extra zero row appended by memset) ----
__global__ void conv_x_k(const float* __restrict__ x, unsigned short* __restrict__ xb) {
    size_t i = ((size_t)blockIdx.x * 256 + threadIdx.x) * 8;
    float4 a = *(const float4*)(x + i);
    float4 b = *(const float4*)(x + i + 4);
    uint4 v;
    v.x = (unsigned)f2bf(a.x) | ((unsigned)f2bf(a.y) << 16);
    v.y = (unsigned)f2bf(a.z) | ((unsigned)f2bf(a.w) << 16);
    v.z = (unsigned)f2bf(b.x) | ((unsigned)f2bf(b.y) << 16);
    v.w = (unsigned)f2bf(b.z) | ((unsigned)f2bf(b.w) << 16);
    *(uint4*)(xb + i) = v;
}

// ---------------- merged weight converter (full-F path): all 3 tensors ------
__global__ void conv_all_k(const float* __restrict__ w1, const float* __restrict__ w3,
                           const float* __restrict__ w2,
                           unsigned short* __restrict__ wb1, unsigned short* __restrict__ wb3,
                           unsigned short* __restrict__ wb2) {
    int z = blockIdx.y;
    const float* s = (z == 0) ? w1 : (z == 1) ? w3 : w2;
    unsigned short* d = (z == 0) ? wb1 : (z == 1) ? wb3 : wb2;
    size_t i = ((size_t)blockIdx.x * 256 + threadIdx.x) * 8;
    float4 a = *(const float4*)(s + i);
    float4 b = *(const float4*)(s + i + 4);
    uint4 v;
    v.x = (unsigned)f2bf(a.x) | ((unsigned)f2bf(a.y) << 16);
    v.y = (unsigned)f2bf(a.z) | ((unsigned)f2bf(a.w) << 16);
    v.z = (unsigned)f2bf(b.x) | ((unsigned)f2bf(b.y) << 16);
    v.w = (unsigned)f2bf(b.z) | ((unsigned)f2bf(b.w) << 16);
    *(uint4*)(d + i) = v;
}

// ---------------- chunked weight converters (fallback when ws is small) -----
__global__ void conv_w13_k(const float* __restrict__ src, unsigned short* __restrict__ dst,
                           int f0, int Fc) {
    int e = blockIdx.y;
    size_t rem = ((size_t)blockIdx.x * 256 + threadIdx.x) * 8;
    const float* s = src + ((size_t)e * FDIM + f0) * HDIM + rem;
    unsigned short* d = dst + (size_t)e * Fc * HDIM + rem;
    float4 a = *(const float4*)(s);
    float4 b = *(const float4*)(s + 4);
    uint4 v;
    v.x = (unsigned)f2bf(a.x) | ((unsigned)f2bf(a.y) << 16);
    v.y = (unsigned)f2bf(a.z) | ((unsigned)f2bf(a.w) << 16);
    v.z = (unsigned)f2bf(b.x) | ((unsigned)f2bf(b.y) << 16);
    v.w = (unsigned)f2bf(b.z) | ((unsigned)f2bf(b.w) << 16);
    *(uint4*)(d) = v;
}

__global__ void conv_w2_k(const float* __restrict__ src, unsigned short* __restrict__ dst,
                          int f0, int Fc, int fcShift) {
    int e = blockIdx.y;
    size_t idx = ((size_t)blockIdx.x * 256 + threadIdx.x) * 8;
    int h = (int)(idx >> fcShift);
    int c = (int)(idx & (size_t)(Fc - 1));
    const float* s = src + ((size_t)e * HDIM + h) * FDIM + f0 + c;
    unsigned short* d = dst + (size_t)e * HDIM * Fc + idx;
    float4 a = *(const float4*)(s);
    float4 b = *(const float4*)(s + 4);
    uint4 v;
    v.x = (unsigned)f2bf(a.x) | ((unsigned)f2bf(a.y) << 16);
    v.y = (unsigned)f2bf(a.z) | ((unsigned)f2bf(a.w) << 16);
    v.z = (unsigned)f2bf(b.x) | ((unsigned)f2bf(b.y) << 16);
    v.w = (unsigned)f2bf(b.z) | ((unsigned)f2bf(b.w) << 16);
    *(uint4*)(d) = v;
}

// ---------------- router: logits, top-2, append to expert lists ----------------
__global__ void router_k(const float* __restrict__ x, const float* __restrict__ gw,
                         float* __restrict__ logits_out, int* __restrict__ cnt,
                         int* __restrict__ list, float* __restrict__ wlist) {
    int w = threadIdx.x >> 6, lane = threadIdx.x & 63;
    int t = blockIdx.x * 4 + w;
    float acc[NE];
#pragma unroll
    for (int e = 0; e < NE; ++e) acc[e] = 0.f;
    for (int i = 0; i < HDIM / 64; ++i) {
        int h = i * 64 + lane;
        float xv = x[(size_t)t * HDIM + h];
#pragma unroll
        for (int e = 0; e < NE; ++e) acc[e] += xv * gw[e * HDIM + h];
    }
#pragma unroll
    for (int e = 0; e < NE; ++e)
#pragma unroll
        for (int off = 32; off; off >>= 1) acc[e] += __shfl_xor(acc[e], off);
    if (lane == 0) {
#pragma unroll
        for (int e = 0; e < NE; ++e) logits_out[(size_t)t * NE + e] = acc[e];
        int e1 = 0;
#pragma unroll
        for (int e = 1; e < NE; ++e) if (acc[e] > acc[e1]) e1 = e;
        int e2 = (e1 == 0) ? 1 : 0;
#pragma unroll
        for (int e = 0; e < NE; ++e) { if (e == e1) continue; if (acc[e] > acc[e2]) e2 = e; }
        float wa = 1.f / (1.f + expf(acc[e2] - acc[e1]));
        float wb = 1.f - wa;
        int p1 = atomicAdd(&cnt[e1], 1); list[e1 * T + p1] = t; wlist[e1 * T + p1] = wa;
        int p2 = atomicAdd(&cnt[e2], 1); list[e2 * T + p2] = t; wlist[e2 * T + p2] = wb;
    }
}

// ---------------- padded exclusive prefix over expert counts ----------------
__global__ void offsets_k(const int* __restrict__ cnt, int* __restrict__ poff) {
    if (threadIdx.x == 0) {
        int o = 0; poff[0] = 0;
        for (int e = 0; e < NE; ++e) { o += ((cnt[e] + 127) >> 7) << 7; poff[e + 1] = o; }
    }
}

// ---------------- compact lists into padded row space ----------------
// pad rows get token index T (the zero row of xb) and weight 0
__global__ void compact_k(const int* __restrict__ cnt, const int* __restrict__ poff,
                          const int* __restrict__ list, const float* __restrict__ wlist,
                          int* __restrict__ tok_row, float* __restrict__ w_row) {
    int gid = blockIdx.x * 256 + threadIdx.x;  // NE*T threads
    int e = gid >> 12, i = gid & (T - 1);
    int pc = poff[e + 1] - poff[e];
    if (i < pc) {
        int row = poff[e] + i;
        if (i < cnt[e]) { tok_row[row] = list[e * T + i]; w_row[row] = wlist[e * T + i]; }
        else           { tok_row[row] = T;               w_row[row] = 0.f; }
    }
}

// ---------------- GEMM1: inter = silu(x@w1^T) * (x@w3^T), gathered rows ------
// Grid: x = f-block (fast) so co-resident blocks span all f for ~24 row strips:
// xb slice stays hot in L2/L3 (read 32x from cache), weights stream once.
// LDS layout invariant: element (row r, colblk cb) of a Nx64 bf16 tile lives at
// byte (r>>3)*1024 + (r&7)*128 + (cb ^ (r&7))*16  (swizzle applied on GLOBAL col).
__global__ __launch_bounds__(256, 3) void gemm1_k(
    const unsigned short* __restrict__ xb, const unsigned short* __restrict__ wb1,
    const unsigned short* __restrict__ wb3, const int* __restrict__ tok_row,
    const int* __restrict__ poff, unsigned short* __restrict__ inter, int Fc) {

    __shared__ __align__(16) unsigned short As[128 * 64];
    __shared__ __align__(16) unsigned short B1[128 * 64];
    __shared__ __align__(16) unsigned short B3[128 * 64];
    __shared__ int toks[128];
    __shared__ int e_sh;

    int row0 = blockIdx.y * 128;
    if (row0 >= poff[NE]) return;
    int tid = threadIdx.x;
    if (tid == 0) { int e = 0; while (row0 >= poff[e + 1]) ++e; e_sh = e; }
    if (tid < 128) toks[tid] = tok_row[row0 + tid];
    __syncthreads();
    int e = e_sh;
    int fr0 = blockIdx.x * 128;
    const unsigned short* w1p = wb1 + ((size_t)e * Fc + fr0) * HDIM;
    const unsigned short* w3p = wb3 + ((size_t)e * Fc + fr0) * HDIM;

    int wv = tid >> 6, lane = tid & 63;
    int quad = lane >> 4, l16 = lane & 15;
    int wm = (wv >> 1) * 64, wn = (wv & 1) * 64;

    int sr = lane >> 3;
    int sc = (lane & 7) ^ sr;
    unsigned a_off[4];
#pragma unroll
    for (int jj = 0; jj < 4; ++jj)
        a_off[jj] = (unsigned)toks[wv * 32 + jj * 8 + sr] * HDIM + sc * 8;
    const unsigned short* w1b = w1p + (size_t)(wv * 32 + sr) * HDIM + sc * 8;
    const unsigned short* w3b = w3p + (size_t)(wv * 32 + sr) * HDIM + sc * 8;

    f32x4 acc1[4][4], acc3[4][4];
#pragma unroll
    for (int a = 0; a < 4; ++a)
#pragma unroll
        for (int b = 0; b < 4; ++b) {
            acc1[a][b] = f32x4{0.f, 0.f, 0.f, 0.f};
            acc3[a][b] = f32x4{0.f, 0.f, 0.f, 0.f};
        }

    for (int k0 = 0; k0 < HDIM; k0 += 64) {
#pragma unroll
        for (int jj = 0; jj < 4; ++jj) {
            int j = wv * 4 + jj;
            cp16(xb + a_off[jj] + k0, As + j * 512);
            cp16(w1b + (size_t)jj * 8 * HDIM + k0, B1 + j * 512);
            cp16(w3b + (size_t)jj * 8 * HDIM + k0, B3 + j * 512);
        }
        __syncthreads();
#pragma unroll
        for (int ks = 0; ks < 2; ++ks) {
            int cb0 = ks * 4 + quad;
            bf16x8 af[4];
#pragma unroll
            for (int mi = 0; mi < 4; ++mi) {
                int m = wm + mi * 16 + l16;
                af[mi] = *(const bf16x8*)(As + m * 64 + ((cb0 ^ (m & 7)) * 8));
            }
#pragma unroll
            for (int ni = 0; ni < 4; ++ni) {
                int n = wn + ni * 16 + l16;
                int boff = n * 64 + ((cb0 ^ (n & 7)) * 8);
                bf16x8 b1f = *(const bf16x8*)(B1 + boff);
                bf16x8 b3f = *(const bf16x8*)(B3 + boff);
#pragma unroll
                for (int mi = 0; mi < 4; ++mi) {
                    acc1[mi][ni] = __builtin_amdgcn_mfma_f32_16x16x32_bf16(af[mi], b1f, acc1[mi][ni], 0, 0, 0);
                    acc3[mi][ni] = __builtin_amdgcn_mfma_f32_16x16x32_bf16(af[mi], b3f, acc3[mi][ni], 0, 0, 0);
                }
            }
        }
        __syncthreads();
    }
#pragma unroll
    for (int mi = 0; mi < 4; ++mi)
#pragma unroll
        for (int ni = 0; ni < 4; ++ni)
#pragma unroll
            for (int r = 0; r < 4; ++r) {
                int m = wm + mi * 16 + quad * 4 + r;
                int n = wn + ni * 16 + l16;
                float v1 = acc1[mi][ni][r], v3 = acc3[mi][ni][r];
                float hval = (v1 / (1.f + __expf(-v1))) * v3;  // silu(v1)*v3
                inter[(size_t)(row0 + m) * Fc + fr0 + n] = f2bf(hval);
            }
}

// ---------------- GEMM2: out[tok] += w_row * (inter @ w2^T) ----------------
// 128x128, 256 threads, grid x = n-block (fast): co-resident blocks share each
// inter strip; wb2 (64 MB) stays L3-resident across strips.
__global__ __launch_bounds__(256, 3) void gemm2_k(
    const unsigned short* __restrict__ inter, const unsigned short* __restrict__ wb2,
    const int* __restrict__ tok_row, const float* __restrict__ w_row,
    const int* __restrict__ poff, float* __restrict__ out, int Fc) {

    __shared__ __align__(16) unsigned short As[128 * 64];
    __shared__ __align__(16) unsigned short Bs[128 * 64];
    __shared__ int e_sh;

    int row0 = blockIdx.y * 128;
    if (row0 >= poff[NE]) return;
    int tid = threadIdx.x;
    if (tid == 0) { int e = 0; while (row0 >= poff[e + 1]) ++e; e_sh = e; }
    __syncthreads();
    int e = e_sh;
    int n0 = blockIdx.x * 128;

    int wv = tid >> 6, lane = tid & 63;
    int quad = lane >> 4, l16 = lane & 15;
    int wm = (wv >> 1) * 64, wn = (wv & 1) * 64;

    int sr = lane >> 3;
    int sc = (lane & 7) ^ sr;
    const unsigned short* a_b = inter + (size_t)(row0 + wv * 32 + sr) * Fc + sc * 8;
    const unsigned short* b_b = wb2 + ((size_t)e * HDIM + n0 + wv * 32 + sr) * Fc + sc * 8;

    f32x4 acc[4][4];
#pragma unroll
    for (int a = 0; a < 4; ++a)
#pragma unroll
        for (int b = 0; b < 4; ++b) acc[a][b] = f32x4{0.f, 0.f, 0.f, 0.f};

    for (int k0 = 0; k0 < Fc; k0 += 64) {
#pragma unroll
        for (int jj = 0; jj < 4; ++jj) {
            int j = wv * 4 + jj;
            cp16(a_b + (size_t)jj * 8 * Fc + k0, As + j * 512);
            cp16(b_b + (size_t)jj * 8 * Fc + k0, Bs + j * 512);
        }
        __syncthreads();
#pragma unroll
        for (int ks = 0; ks < 2; ++ks) {
            int cb0 = ks * 4 + quad;
            bf16x8 af[4];
#pragma unroll
            for (int mi = 0; mi < 4; ++mi) {
                int m = wm + mi * 16 + l16;
                af[mi] = *(const bf16x8*)(As + m * 64 + ((cb0 ^ (m & 7)) * 8));
            }
#pragma unroll
            for (int ni = 0; ni < 4; ++ni) {
                int n = wn + ni * 16 + l16;
                bf16x8 bf = *(const bf16x8*)(Bs + n * 64 + ((cb0 ^ (n & 7)) * 8));
#pragma unroll
                for (int mi = 0; mi < 4; ++mi)
                    acc[mi][ni] = __builtin_amdgcn_mfma_f32_16x16x32_bf16(af[mi], bf, acc[mi][ni], 0, 0, 0);
            }
        }
        __syncthreads();
    }
#pragma unroll
    for (int mi = 0; mi < 4; ++mi)
#pragma unroll
        for (int r = 0; r < 4; ++r) {
            int m = wm + mi * 16 + quad * 4 + r;
            int grow = row0 + m;
            float wr = w_row[grow];
            if (wr != 0.f) {
                int t = tok_row[grow];
                float* op = out + (size_t)t * HDIM + n0;
#pragma unroll
                for (int ni = 0; ni < 4; ++ni)
                    atomicAdd(op + wn + ni * 16 + l16, wr * acc[mi][ni][r]);
            }
        }
}

extern "C" void kernel_launch(void* const* d_in, const int* in_sizes, int n_in,
                              void* d_out, int out_size, void* d_ws, size_t ws_size,
                              hipStream_t stream) {
    const float* x  = (const float*)d_in[0];
    const float* gw = (const float*)d_in[1];
    const float* w1 = (const float*)d_in[2];
    const float* w2 = (const float*)d_in[3];
    const float* w3 = (const float*)d_in[4];
    float* out = (float*)d_out;
    float* logits = out + (size_t)T * HDIM;

    char* ws = (char*)d_ws;
    size_t off = 0;
    auto alloc = [&](size_t b) {
        off = (off + 255) & ~(size_t)255;
        void* p = ws + off;
        off += b;
        return p;
    };
    int* cnt        = (int*)alloc(NE * 4);
    int* poff       = (int*)alloc((NE + 1) * 4);
    int* list       = (int*)alloc((size_t)NE * T * 4);
    float* wlist    = (float*)alloc((size_t)NE * T * 4);
    int* tok_row    = (int*)alloc(MAXROWS * 4);
    float* w_row    = (float*)alloc(MAXROWS * 4);
    unsigned short* xb = (unsigned short*)alloc((size_t)(T + 1) * HDIM * 2);  // +1 zero row
    size_t fixed_off = off;

    int Fc = 4096, fcShift = 12;
    for (;;) {
        size_t need = fixed_off + 3 * ((size_t)NE * Fc * HDIM * 2) + (size_t)MAXROWS * Fc * 2 + 1024;
        if (need <= ws_size || Fc == 512) break;
        Fc >>= 1; fcShift -= 1;
    }
    unsigned short* wb1 = (unsigned short*)alloc((size_t)NE * Fc * HDIM * 2);
    unsigned short* wb3 = (unsigned short*)alloc((size_t)NE * Fc * HDIM * 2);
    unsigned short* wb2 = (unsigned short*)alloc((size_t)NE * HDIM * Fc * 2);
    unsigned short* inter = (unsigned short*)alloc((size_t)MAXROWS * Fc * 2);

    hipMemsetAsync(cnt, 0, NE * 4, stream);
    hipMemsetAsync(out, 0, (size_t)T * HDIM * 4, stream);
    hipMemsetAsync(xb + (size_t)T * HDIM, 0, HDIM * 2, stream);
    conv_x_k<<<(T * HDIM / 8) / 256, 256, 0, stream>>>(x, xb);
    router_k<<<T / 4, 256, 0, stream>>>(x, gw, logits, cnt, list, wlist);
    offsets_k<<<1, 64, 0, stream>>>(cnt, poff);
    compact_k<<<NE * T / 256, 256, 0, stream>>>(cnt, poff, list, wlist, tok_row, w_row);

    int nMT = MAXROWS / 128;  // 72
    if (Fc == FDIM) {
        conv_all_k<<<dim3((size_t)NE * FDIM * HDIM / 8 / 256, 3), 256, 0, stream>>>(
            w1, w3, w2, wb1, wb3, wb2);
        gemm1_k<<<dim3(FDIM / 128, nMT), 256, 0, stream>>>(xb, wb1, wb3, tok_row, poff, inter, FDIM);
        gemm2_k<<<dim3(HDIM / 128, nMT), 256, 0, stream>>>(inter, wb2, tok_row, w_row, poff, out, FDIM);
    } else {
        for (int f0 = 0; f0 < FDIM; f0 += Fc) {
            conv_w13_k<<<dim3(Fc / 2, NE), 256, 0, stream>>>(w1, wb1, f0, Fc);
            conv_w13_k<<<dim3(Fc / 2, NE), 256, 0, stream>>>(w3, wb3, f0, Fc);
            conv_w2_k<<<dim3(HDIM * Fc / 2048, NE), 256, 0, stream>>>(w2, wb2, f0, Fc, fcShift);
            gemm1_k<<<dim3(Fc / 128, nMT), 256, 0, stream>>>(xb, wb1, wb3, tok_row, poff, inter, Fc);
            gemm2_k<<<dim3(HDIM / 128, nMT), 256, 0, stream>>>(inter, wb2, tok_row, w_row, poff, out, Fc);
        }
    }
}